// Round 1
// 407.161 us; speedup vs baseline: 1.1456x; 1.1456x over previous
//
#include <hip/hip_runtime.h>

// AttentionPooling: N=262144, DIM=256, H=4, HD=64, B=4096 (batch sorted).
// R6 vs R5 (466 us total; attn_pool 208 us, VALUBusy 21%, HBM 8%, MfmaUtil 0):
//   Diagnosis: old in-block epilogue gathered value_w rows per-lane -- each wave
//   load touched 64 distinct 64B lines (t=tid&255 consecutive -> 1KB-strided rows).
//   256 gather-instrs/block x 4096 blocks ~ 67M line requests ~ 260k TCP cyc/CU
//   ~ 110 us, invariant across R4->R5 (both ~205 us). Remaining ~90 us: main-loop
//   loads issue only after the prior iteration's shuffle chain (1 latency
//   window/iter, ~1 load-instr per 487 cyc/CU observed).
//   Fix A: value projection moved to a segment-tiled kernel (val_proj) reading
//          pre-transposed value_w (vwT4[jj][t] j-packed, coalesced) amortized over
//          TB=8 segments; attn_pool stores raw S + esum (coalesced, 17 MB ws).
//          Fallbacks if ws too small: MODE1 fused coalesced-vwT, MODE2 old gather.
//   Fix B: depth-1 software prefetch of the next node-pair in the main loop.

constexpr int DIM = 256;
constexpr int NH  = 4;
constexpr int HD  = 64;
constexpr float SCL  = 0.125f;   // HD^-0.5
constexpr float EPSV = 1e-8f;

// workspace layout (float offsets)
constexpr int WS_QW   = 0;       // 1024 floats: folded query.key_w
constexpr int WS_QB   = 1024;    // 4 floats
constexpr int WS_OFFS = 1088;    // B+1 ints
constexpr int WS_VWT  = 8192;    // 65536 floats: float4[jj=0..63][t=0..255] = value_w[t][4jj..4jj+3]
constexpr int WS_SRAW = 73728;   // B*1024 floats raw S; esum (B*4) follows

// ---- prep: qw[h][j] = sum_d query[h,d]*key_w[h*64+d, j]; qb[h] = q . key_b ----
__global__ void prep_qw(const float* __restrict__ query,
                        const float* __restrict__ key_w,
                        const float* __restrict__ key_b,
                        float* __restrict__ ws){
  int t = blockIdx.x * 256 + threadIdx.x;   // 0..1023
  int h = t >> 8, j = t & 255;
  float acc = 0.f;
  #pragma unroll 8
  for (int d = 0; d < HD; ++d)
    acc += query[h*HD+d] * key_w[(size_t)(h*HD+d)*DIM + j];
  ws[WS_QW + t] = acc;
  if (j == 0){
    float bb = 0.f;
    for (int d = 0; d < HD; ++d)
      bb += query[h*HD+d] * key_b[h*HD+d];
    ws[WS_QB + h] = bb;
  }
}

// ---- prep: transpose value_w into j-packed layout for coalesced reads ----
// vwT4[jj*256 + t] = {value_w[t][4jj], value_w[t][4jj+1], value_w[t][4jj+2], value_w[t][4jj+3]}
__global__ void prep_vwt(const float* __restrict__ value_w, float* __restrict__ ws){
  int jj = blockIdx.x;        // 0..63
  int t  = threadIdx.x;       // 0..255
  float4 v = *(const float4*)(value_w + (size_t)t*DIM + 4*jj);  // gather read (one-time, 256 KB)
  ((float4*)(ws + WS_VWT))[jj*256 + t] = v;                     // coalesced write
}

// ---- segment offsets: offs[b] = first i with batch[i] >= b; offs[B] = N ----
__global__ void seg_offsets(const int* __restrict__ batch32,
                            int* __restrict__ offs, int N, int B){
  int i = blockIdx.x * 256 + threadIdx.x;
  if (i >= N) return;
  const bool is64 = (batch32[N-1] == 0);   // int64 layout: high word of last elem is 0
  int v  = is64 ? batch32[2*i] : batch32[i];
  int vp = (i == 0) ? -1 : (is64 ? batch32[2*(i-1)] : batch32[i-1]);
  for (int b = vp + 1; b <= v; ++b) offs[b] = i;
  if (i == N-1)
    for (int b = v + 1; b <= B; ++b) offs[b] = N;
}

// ---- main: one block (512 thr = 8 waves = 16 streams) per segment ----
// MODE 0: store raw S + esum to workspace (val_proj does the projection)
// MODE 1: fused epilogue via coalesced vwT (ws too small for S, has vwT)
// MODE 2: fused epilogue via value_w row gather (last-resort, old R5 path)
template<int MODE>
__global__ __launch_bounds__(512, 4)
void attn_pool(const float* __restrict__ x,
               const int* __restrict__ offs,
               const float* __restrict__ ws,
               const float* __restrict__ value_w,
               const float* __restrict__ value_b,
               float* __restrict__ sraw,
               float* __restrict__ esum,
               float* __restrict__ out){
  constexpr int LDSF = (MODE == 0) ? (8192 + 32)
                     : (MODE == 1) ? (8192 + 32 + 1024 + 2048 + 8)
                                   : (8192 + 32 + 1024 + 512 + 8);
  __shared__ __align__(16) float lds[LDSF];
  float* S_all    = lds;          // [8][4][256] per-wave partial S (32 KB)
  float* sums_all = lds + 8192;   // [8][4]

  const int b   = blockIdx.x;
  const int tid = threadIdx.x;
  const int seg_start = offs[b];
  const int seg_end   = offs[b+1];

  const int wave = tid >> 6, lane = tid & 63;
  const int half = lane >> 5, sl = lane & 31;   // half-wave = one stream
  const int sigma = wave * 2 + half;            // stream id 0..15

  // lane-resident qw fragment: columns sl*8 .. sl*8+7, all 4 heads
  float qwr[NH][8];
  #pragma unroll
  for (int h = 0; h < NH; ++h){
    const float4* q4 = (const float4*)(ws + WS_QW + h*DIM + sl*8);
    float4 a = q4[0], c = q4[1];
    qwr[h][0]=a.x; qwr[h][1]=a.y; qwr[h][2]=a.z; qwr[h][3]=a.w;
    qwr[h][4]=c.x; qwr[h][5]=c.y; qwr[h][6]=c.z; qwr[h][7]=c.w;
  }
  float qb[NH];
  #pragma unroll
  for (int h = 0; h < NH; ++h) qb[h] = ws[WS_QB + h];

  float Sacc[NH][8];
  #pragma unroll
  for (int h = 0; h < NH; ++h)
    #pragma unroll
    for (int c = 0; c < 8; ++c) Sacc[h][c] = 0.f;
  float se[NH] = {0.f, 0.f, 0.f, 0.f};

  const float4* xr4 = (const float4*)x;   // one row = 64 float4
  const float4 Z = make_float4(0.f, 0.f, 0.f, 0.f);

  // stream sigma handles node pairs (n0, n0+1), n0 = seg_start + 2*sigma + 32k.
  // Depth-1 prefetch: next pair's loads issue BEFORE this pair's chain.
  int n0 = seg_start + sigma*2;
  bool v0 = n0 < seg_end;
  bool v1 = n0 + 1 < seg_end;
  float4 a0=Z, b0=Z, a1=Z, b1=Z;
  if (v0){ a0 = xr4[(size_t)n0*64 + sl*2];     b0 = xr4[(size_t)n0*64 + sl*2 + 1]; }
  if (v1){ a1 = xr4[(size_t)(n0+1)*64 + sl*2]; b1 = xr4[(size_t)(n0+1)*64 + sl*2 + 1]; }

  while (v0){
    const int nn = n0 + 32;
    const bool w0 = nn < seg_end;
    const bool w1 = nn + 1 < seg_end;
    float4 c0=Z, d0=Z, c1=Z, d1=Z;
    if (w0){ c0 = xr4[(size_t)nn*64 + sl*2];     d0 = xr4[(size_t)nn*64 + sl*2 + 1]; }
    if (w1){ c1 = xr4[(size_t)(nn+1)*64 + sl*2]; d1 = xr4[(size_t)(nn+1)*64 + sl*2 + 1]; }

    float xv0[8] = {a0.x,a0.y,a0.z,a0.w,b0.x,b0.y,b0.z,b0.w};
    float xv1[8] = {a1.x,a1.y,a1.z,a1.w,b1.x,b1.y,b1.z,b1.w};

    float p0[NH], p1[NH];
    #pragma unroll
    for (int h = 0; h < NH; ++h){
      float s0 = 0.f, s1 = 0.f;
      #pragma unroll
      for (int c = 0; c < 8; ++c){ s0 += qwr[h][c]*xv0[c]; s1 += qwr[h][c]*xv1[c]; }
      p0[h] = s0; p1[h] = s1;
    }
    // 8 independent butterfly chains (4 heads x 2 nodes), interleaved per stage
    #pragma unroll
    for (int m = 1; m < 32; m <<= 1){
      #pragma unroll
      for (int h = 0; h < NH; ++h){
        p0[h] += __shfl_xor(p0[h], m, 64);
        p1[h] += __shfl_xor(p1[h], m, 64);
      }
    }
    const float g1 = v1 ? 1.f : 0.f;
    #pragma unroll
    for (int h = 0; h < NH; ++h){
      float e0 = __expf((p0[h] + qb[h]) * SCL);
      float e1 = __expf((p1[h] + qb[h]) * SCL) * g1;  // xv1 zeroed when !v1
      se[h] += e0 + e1;
      #pragma unroll
      for (int c = 0; c < 8; ++c)
        Sacc[h][c] += e0*xv0[c] + e1*xv1[c];
    }
    n0 = nn; v0 = w0; v1 = w1;
    a0 = c0; b0 = d0; a1 = c1; b1 = d1;
  }

  // combine the two streams of each wave (same columns, different nodes)
  #pragma unroll
  for (int h = 0; h < NH; ++h){
    se[h] += __shfl_xor(se[h], 32, 64);
    #pragma unroll
    for (int c = 0; c < 8; ++c) Sacc[h][c] += __shfl_xor(Sacc[h][c], 32, 64);
  }
  if (half == 0){
    #pragma unroll
    for (int h = 0; h < NH; ++h){
      float4 lo = make_float4(Sacc[h][0], Sacc[h][1], Sacc[h][2], Sacc[h][3]);
      float4 hi = make_float4(Sacc[h][4], Sacc[h][5], Sacc[h][6], Sacc[h][7]);
      float4* dst = (float4*)&S_all[wave*1024 + h*256 + sl*8];
      dst[0] = lo; dst[1] = hi;
    }
    if (sl == 0){
      #pragma unroll
      for (int h = 0; h < NH; ++h) sums_all[wave*4 + h] = se[h];
    }
  }
  __syncthreads();

  if constexpr (MODE == 0){
    // reduce 8 wave-copies, store raw S + esum (coalesced); val_proj finishes.
    #pragma unroll
    for (int k = 0; k < 2; ++k){
      const int idx = tid + k*512;
      float s = 0.f;
      #pragma unroll
      for (int w = 0; w < 8; ++w) s += S_all[w*1024 + idx];
      sraw[(size_t)b*1024 + idx] = s;
    }
    if (tid < NH){
      float tot = 0.f;
      #pragma unroll
      for (int w = 0; w < 8; ++w) tot += sums_all[w*4 + tid];
      esum[b*4 + tid] = tot;
    }
  } else if constexpr (MODE == 1){
    float* Sfin  = lds + 8224;   // [4][256]
    float* ep    = lds + 9248;   // [8][256]
    float* invs  = lds + 11296;  // [4]
    float* wsums = lds + 11300;  // [4]
    #pragma unroll
    for (int k = 0; k < 2; ++k){
      const int idx = tid + k*512;
      float s = 0.f;
      #pragma unroll
      for (int w = 0; w < 8; ++w) s += S_all[w*1024 + idx];
      Sfin[idx] = s;
    }
    if (tid < NH){
      float tot = 0.f;
      #pragma unroll
      for (int w = 0; w < 8; ++w) tot += sums_all[w*4 + tid];
      float inv = 1.f / (tot + EPSV);
      invs[tid] = inv; wsums[tid] = tot * inv;
    }
    __syncthreads();
    // coalesced epilogue: wave w owns jj-slice [8w,8w+8); lane owns t = 4*lane..4*lane+3
    const float4* vwt4 = (const float4*)(ws + WS_VWT);
    const int hh = lane >> 4;                 // head for t=4*lane
    float4 acc = make_float4(0.f, 0.f, 0.f, 0.f);
    for (int jj = wave*8; jj < wave*8 + 8; ++jj){
      float4 q0 = vwt4[jj*256 + 4*lane + 0];
      float4 q1 = vwt4[jj*256 + 4*lane + 1];
      float4 q2 = vwt4[jj*256 + 4*lane + 2];
      float4 q3 = vwt4[jj*256 + 4*lane + 3];
      float4 sf = *(const float4*)&Sfin[hh*256 + 4*jj];
      acc.x += q0.x*sf.x + q0.y*sf.y + q0.z*sf.z + q0.w*sf.w;
      acc.y += q1.x*sf.x + q1.y*sf.y + q1.z*sf.z + q1.w*sf.w;
      acc.z += q2.x*sf.x + q2.y*sf.y + q2.z*sf.z + q2.w*sf.w;
      acc.w += q3.x*sf.x + q3.y*sf.y + q3.z*sf.z + q3.w*sf.w;
    }
    *(float4*)&ep[wave*256 + 4*lane] = acc;
    __syncthreads();
    if (tid < 256){
      const int t = tid, h2 = t >> 6;
      float s = 0.f;
      #pragma unroll
      for (int w = 0; w < 8; ++w) s += ep[w*256 + t];
      out[(size_t)b*256 + t] = s * invs[h2] + wsums[h2] * value_b[t];
    }
  } else {
    // MODE 2: last-resort old gather epilogue
    float* Sfin  = lds + 8224;   // [4][256]
    float* ep2   = lds + 9248;   // [2][256]
    float* invs  = lds + 9760;   // [4]
    float* wsums = lds + 9764;   // [4]
    #pragma unroll
    for (int k = 0; k < 2; ++k){
      const int idx = tid + k*512;
      float s = 0.f;
      #pragma unroll
      for (int w = 0; w < 8; ++w) s += S_all[w*1024 + idx];
      Sfin[idx] = s;
    }
    if (tid < NH){
      float tot = 0.f;
      #pragma unroll
      for (int w = 0; w < 8; ++w) tot += sums_all[w*4 + tid];
      float inv = 1.f / (tot + EPSV);
      invs[tid] = inv; wsums[tid] = tot * inv;
    }
    __syncthreads();
    const int t = tid & 255, part = tid >> 8;
    const int h2 = t >> 6;
    const float4* vrow = (const float4*)(value_w + (size_t)t * DIM) + part*32;
    const float4* sp   = (const float4*)&Sfin[h2*256] + part*32;
    float acc = 0.f;
    #pragma unroll
    for (int q = 0; q < 32; ++q){
      float4 r = vrow[q];
      float4 s = sp[q];
      acc += r.x*s.x + r.y*s.y + r.z*s.z + r.w*s.w;
    }
    ep2[part*256 + t] = acc;
    __syncthreads();
    if (part == 0)
      out[(size_t)b * DIM + t] = (ep2[t] + ep2[256 + t]) * invs[h2] + wsums[h2] * value_b[t];
  }
}

// ---- value projection: TB=8 segments per block, coalesced vwT, reused 8x ----
// out[b,t] = inv * (value_w[t,:] . Sraw[b,h,:]) + (esum*inv) * value_b[t]
__global__ __launch_bounds__(256, 4)
void val_proj(const float* __restrict__ ws,
              const float* __restrict__ sraw,
              const float* __restrict__ esum,
              const float* __restrict__ value_b,
              float* __restrict__ out){
  constexpr int TB = 8;
  __shared__ __align__(16) float Sl[NH*DIM*TB];   // [h][j][i], 32 KB
  const int b0  = blockIdx.x * TB;
  const int tid = threadIdx.x;

  // load 8 segments' raw S: global coalesced, LDS [rem][i] layout
  for (int idx = tid; idx < NH*DIM*TB; idx += 256){
    const int i = idx >> 10, rem = idx & 1023;    // rem = h*256+j
    Sl[rem*TB + i] = sraw[(size_t)(b0 + i)*1024 + rem];
  }
  __syncthreads();

  const int t = tid, h = t >> 6;                  // per-wave-uniform h
  const float4* vwt4 = (const float4*)(ws + WS_VWT);
  float acc[TB];
  #pragma unroll
  for (int i = 0; i < TB; ++i) acc[i] = 0.f;

  #pragma unroll 4
  for (int jj = 0; jj < 64; ++jj){
    const float4 w4 = vwt4[jj*256 + t];           // coalesced, L2-resident
    #pragma unroll
    for (int r = 0; r < 4; ++r){
      const float* sp = &Sl[(h*256 + 4*jj + r)*TB];   // broadcast reads
      const float4 s0 = *(const float4*)sp;
      const float4 s1 = *(const float4*)(sp + 4);
      const float wr = (&w4.x)[r];
      acc[0] += wr*s0.x; acc[1] += wr*s0.y; acc[2] += wr*s0.z; acc[3] += wr*s0.w;
      acc[4] += wr*s1.x; acc[5] += wr*s1.y; acc[6] += wr*s1.z; acc[7] += wr*s1.w;
    }
  }
  const float vb = value_b[t];
  #pragma unroll
  for (int i = 0; i < TB; ++i){
    const float es  = esum[(b0 + i)*4 + h];
    const float inv = 1.f / (es + EPSV);
    out[(size_t)(b0 + i)*256 + t] = acc[i]*inv + es*inv*vb;
  }
}

extern "C" void kernel_launch(void* const* d_in, const int* in_sizes, int n_in,
                              void* d_out, int out_size, void* d_ws, size_t ws_size,
                              hipStream_t stream){
  const float* x       = (const float*)d_in[0];
  const int*   batch   = (const int*)d_in[1];
  const float* query   = (const float*)d_in[2];
  const float* key_w   = (const float*)d_in[3];
  const float* key_b   = (const float*)d_in[4];
  const float* value_w = (const float*)d_in[5];
  const float* value_b = (const float*)d_in[6];
  float* ws  = (float*)d_ws;
  float* out = (float*)d_out;

  const int N = in_sizes[1];        // 262144
  const int B = out_size / DIM;     // 4096

  int*   offs = (int*)(ws + WS_OFFS);
  float* sraw = ws + WS_SRAW;
  float* esum = ws + WS_SRAW + (size_t)B*1024;

  const size_t need_split = ((size_t)WS_SRAW + (size_t)B*1024 + (size_t)B*4) * sizeof(float);
  const size_t need_vwt   = ((size_t)WS_VWT + 65536) * sizeof(float);

  prep_qw<<<4, 256, 0, stream>>>(query, key_w, key_b, ws);
  seg_offsets<<<(N + 255) / 256, 256, 0, stream>>>(batch, offs, N, B);

  if (ws_size >= need_split){
    prep_vwt<<<64, 256, 0, stream>>>(value_w, ws);
    attn_pool<0><<<B, 512, 0, stream>>>(x, offs, ws, value_w, value_b, sraw, esum, nullptr);
    val_proj<<<B / 8, 256, 0, stream>>>(ws, sraw, esum, value_b, out);
  } else if (ws_size >= need_vwt){
    prep_vwt<<<64, 256, 0, stream>>>(value_w, ws);
    attn_pool<1><<<B, 512, 0, stream>>>(x, offs, ws, value_w, value_b, nullptr, nullptr, out);
  } else {
    attn_pool<2><<<B, 512, 0, stream>>>(x, offs, ws, value_w, value_b, nullptr, nullptr, out);
  }
}